// Round 7
// baseline (3233.187 us; speedup 1.0000x reference)
//
#include <hip/hip_runtime.h>
#include <hip/hip_bf16.h>

// VQ-VAE forward. Index path: fp32-per-op semantics w/ fp64 internal accumulation
// via f64 MFMA (runtime layout probes), fp32 LDS staging + register-prefetch
// software pipeline. Argmin via packed-key atomicMin. Decoder: bf16 MFMA.
// Outputs (flat fp32): recon[16384*1024], loss[1], indices-as-float[16384].

#define B_    16384
#define INDIM 1024
#define HID   2048
#define KCB   8192
#define DDIM  128

typedef __bf16  bf16x8   __attribute__((ext_vector_type(8)));
typedef float   floatx4  __attribute__((ext_vector_type(4)));
typedef double  doublex4 __attribute__((ext_vector_type(4)));

__device__ __forceinline__ unsigned long long pack_key(float d, int code)
{
    unsigned int u = __float_as_uint(d);
    u = (u & 0x80000000u) ? ~u : (u | 0x80000000u);   // total order matching float <
    return ((unsigned long long)u << 32) | (unsigned int)code;
}

// ---------------------------------------------------------------------------
// fp32-in GEMM, f64 MFMA accumulate, single fp32 rounding (+opt relu).
// BM=128 BN=64 BK=32; 4 waves 2x2, wave tile 64x32 via 4x2 mfma_f64_16x16x4.
// fp32 LDS staging (cvt on read), register prefetch pipeline, probe epilogue.
// ---------------------------------------------------------------------------
template <int ACT>
__launch_bounds__(256)
__global__ void gemm_f64_mfma(const float* __restrict__ A, const float* __restrict__ Bm,
                              const float* __restrict__ bias, float* __restrict__ Cout,
                              int M, int N, int K)
{
    __shared__ float As[128 * 36];   // [m][k] natural, stride 36 (2-way max)
    __shared__ float Bs[32 * 72];    // [k][n] natural, stride 72 (2-way max)

    const int t    = threadIdx.x;
    const int m0   = blockIdx.y * 128, n0 = blockIdx.x * 64;
    const int wave = t >> 6, lane = t & 63;
    const int wr   = (wave >> 1) * 64, wc = (wave & 1) * 32;
    const int quad = lane >> 4, l16 = lane & 15;

    // Layout probe: self-correcting for any bijective lane mapping.
    doublex4 p0 = {0.0, 0.0, 0.0, 0.0};
    doublex4 prow = __builtin_amdgcn_mfma_f64_16x16x4f64((double)l16, 1.0, p0, 0, 0, 0);
    doublex4 pcol = __builtin_amdgcn_mfma_f64_16x16x4f64(1.0, (double)l16, p0, 0, 0, 0);
    int rowmap[4], colmap[4];
#pragma unroll
    for (int r = 0; r < 4; ++r) {
        rowmap[r] = (int)(prow[r] * 0.25);
        colmap[r] = (int)(pcol[r] * 0.25);
    }

    doublex4 acc[4][2];
#pragma unroll
    for (int i = 0; i < 4; ++i)
#pragma unroll
        for (int j = 0; j < 2; ++j) acc[i][j] = (doublex4){0.0, 0.0, 0.0, 0.0};

    // prefetch regs: A 128x32 = 4 float4/thread, B 32x64 = 2 float4/thread
    float4 pA[4], pB[2];
#pragma unroll
    for (int s = 0; s < 4; ++s) {
        int c = t + s * 256, r = c >> 3, c4 = (c & 7) * 4;
        pA[s] = *(const float4*)(A + (size_t)(m0 + r) * K + c4);
    }
#pragma unroll
    for (int s = 0; s < 2; ++s) {
        int c = t + s * 256, r = c >> 4, c4 = (c & 15) * 4;
        pB[s] = *(const float4*)(Bm + (size_t)r * N + n0 + c4);
    }

    for (int k0 = 0; k0 < K; k0 += 32) {
        __syncthreads();   // previous compute done -> safe to overwrite LDS
#pragma unroll
        for (int s = 0; s < 4; ++s) {
            int c = t + s * 256, r = c >> 3, c4 = (c & 7) * 4;
            *(float4*)&As[r * 36 + c4] = pA[s];
        }
#pragma unroll
        for (int s = 0; s < 2; ++s) {
            int c = t + s * 256, r = c >> 4, c4 = (c & 15) * 4;
            *(float4*)&Bs[r * 72 + c4] = pB[s];
        }
        __syncthreads();   // writes visible
        if (k0 + 32 < K) {   // prefetch next tile BEFORE compute (latency hiding)
#pragma unroll
            for (int s = 0; s < 4; ++s) {
                int c = t + s * 256, r = c >> 3, c4 = (c & 7) * 4;
                pA[s] = *(const float4*)(A + (size_t)(m0 + r) * K + k0 + 32 + c4);
            }
#pragma unroll
            for (int s = 0; s < 2; ++s) {
                int c = t + s * 256, r = c >> 4, c4 = (c & 15) * 4;
                pB[s] = *(const float4*)(Bm + (size_t)(k0 + 32 + r) * N + n0 + c4);
            }
        }
#pragma unroll
        for (int ks = 0; ks < 32; ks += 4) {
            int ka = ks + quad;
            double a[4], b[2];
#pragma unroll
            for (int i = 0; i < 4; ++i) a[i] = (double)As[(wr + i * 16 + l16) * 36 + ka];
#pragma unroll
            for (int j = 0; j < 2; ++j) b[j] = (double)Bs[ka * 72 + wc + j * 16 + l16];
#pragma unroll
            for (int i = 0; i < 4; ++i)
#pragma unroll
                for (int j = 0; j < 2; ++j)
                    acc[i][j] = __builtin_amdgcn_mfma_f64_16x16x4f64(a[i], b[j], acc[i][j], 0, 0, 0);
        }
    }

#pragma unroll
    for (int i = 0; i < 4; ++i)
#pragma unroll
        for (int j = 0; j < 2; ++j)
#pragma unroll
            for (int r = 0; r < 4; ++r) {
                int row = m0 + wr + i * 16 + rowmap[r];
                int col = n0 + wc + j * 16 + colmap[r];
                float f = (float)(acc[i][j][r] + (double)bias[col]);  // single fp32 round
                if (ACT == 1) f = fmaxf(f, 0.f);
                Cout[(size_t)row * N + col] = f;
            }
}

// ---------------------------------------------------------------------------
// rownorm32[k] = fl32( sum_fp64( fl32(row[k][d]^2) ) ). One wave per row.
// ---------------------------------------------------------------------------
__global__ void rownorm_kernel(const float* __restrict__ M, float* __restrict__ nrm)
{
    int k = blockIdx.x * 4 + (threadIdx.x >> 6);
    int lane = threadIdx.x & 63;
    float2 c = *(const float2*)(M + (size_t)k * DDIM + lane * 2);
    float q0 = c.x * c.x;
    float q1 = c.y * c.y;
    double s = (double)q0 + (double)q1;
#pragma unroll
    for (int off = 32; off > 0; off >>= 1) s += __shfl_down(s, off);
    if (lane == 0) nrm[k] = (float)s;
}

// ---------------------------------------------------------------------------
// Score: f64 MFMA z.c per (64-row,128-code) tile; fp32 dist chain
// d = fl32(fl32(nz - 2*s32) + cn); packed-key LDS atomicMin -> global atomicMin.
// fp32 LDS staging + register prefetch, BK=32 (4 iterations over D=128).
// ---------------------------------------------------------------------------
__launch_bounds__(256)
__global__ void score_argmin_mfma(const float* __restrict__ z, const float* __restrict__ cb,
                                  const float* __restrict__ nz32, const float* __restrict__ cn32,
                                  unsigned long long* __restrict__ gbest)
{
    __shared__ float zs[64 * 36];     // [m][k] stride 36
    __shared__ float cs[128 * 36];    // [n][k] stride 36
    __shared__ unsigned long long best[64];

    const int t    = threadIdx.x;
    const int m0   = blockIdx.y * 64;    // rows
    const int n0   = blockIdx.x * 128;   // codes
    const int wave = t >> 6, lane = t & 63;
    const int wr   = (wave >> 1) * 32, wc = (wave & 1) * 64;
    const int quad = lane >> 4, l16 = lane & 15;

    if (t < 64) best[t] = ~0ull;

    doublex4 p0 = {0.0, 0.0, 0.0, 0.0};
    doublex4 prow = __builtin_amdgcn_mfma_f64_16x16x4f64((double)l16, 1.0, p0, 0, 0, 0);
    doublex4 pcol = __builtin_amdgcn_mfma_f64_16x16x4f64(1.0, (double)l16, p0, 0, 0, 0);
    int rowmap[4], colmap[4];
#pragma unroll
    for (int r = 0; r < 4; ++r) {
        rowmap[r] = (int)(prow[r] * 0.25);
        colmap[r] = (int)(pcol[r] * 0.25);
    }

    doublex4 acc[2][4];
#pragma unroll
    for (int i = 0; i < 2; ++i)
#pragma unroll
        for (int j = 0; j < 4; ++j) acc[i][j] = (doublex4){0.0, 0.0, 0.0, 0.0};

    // prefetch regs: z 64x32 = 2 float4/thread, cb 128x32 = 4 float4/thread
    float4 pZ[2], pC[4];
#pragma unroll
    for (int s = 0; s < 2; ++s) {
        int c = t + s * 256, r = c >> 3, c4 = (c & 7) * 4;
        pZ[s] = *(const float4*)(z + (size_t)(m0 + r) * DDIM + c4);
    }
#pragma unroll
    for (int s = 0; s < 4; ++s) {
        int c = t + s * 256, r = c >> 3, c4 = (c & 7) * 4;
        pC[s] = *(const float4*)(cb + (size_t)(n0 + r) * DDIM + c4);
    }

    for (int k0 = 0; k0 < DDIM; k0 += 32) {
        __syncthreads();
#pragma unroll
        for (int s = 0; s < 2; ++s) {
            int c = t + s * 256, r = c >> 3, c4 = (c & 7) * 4;
            *(float4*)&zs[r * 36 + c4] = pZ[s];
        }
#pragma unroll
        for (int s = 0; s < 4; ++s) {
            int c = t + s * 256, r = c >> 3, c4 = (c & 7) * 4;
            *(float4*)&cs[r * 36 + c4] = pC[s];
        }
        __syncthreads();
        if (k0 + 32 < DDIM) {
#pragma unroll
            for (int s = 0; s < 2; ++s) {
                int c = t + s * 256, r = c >> 3, c4 = (c & 7) * 4;
                pZ[s] = *(const float4*)(z + (size_t)(m0 + r) * DDIM + k0 + 32 + c4);
            }
#pragma unroll
            for (int s = 0; s < 4; ++s) {
                int c = t + s * 256, r = c >> 3, c4 = (c & 7) * 4;
                pC[s] = *(const float4*)(cb + (size_t)(n0 + r) * DDIM + k0 + 32 + c4);
            }
        }
#pragma unroll
        for (int ks = 0; ks < 32; ks += 4) {
            int ka = ks + quad;
            double a[2], b[4];
#pragma unroll
            for (int i = 0; i < 2; ++i) a[i] = (double)zs[(wr + i * 16 + l16) * 36 + ka];
#pragma unroll
            for (int j = 0; j < 4; ++j) b[j] = (double)cs[(wc + j * 16 + l16) * 36 + ka];
#pragma unroll
            for (int i = 0; i < 2; ++i)
#pragma unroll
                for (int j = 0; j < 4; ++j)
                    acc[i][j] = __builtin_amdgcn_mfma_f64_16x16x4f64(a[i], b[j], acc[i][j], 0, 0, 0);
        }
    }

#pragma unroll
    for (int i = 0; i < 2; ++i)
#pragma unroll
        for (int r = 0; r < 4; ++r) {
            int   lrow = wr + i * 16 + rowmap[r];
            float nz   = nz32[m0 + lrow];
            float bd   = 3.4e38f; int bc = 0x7fffffff;
#pragma unroll
            for (int j = 0; j < 4; ++j) {
                int   code = n0 + wc + j * 16 + colmap[r];
                float s32  = (float)acc[i][j][r];
                float d    = (nz - 2.0f * s32) + cn32[code];
                if (d < bd || (d == bd && code < bc)) { bd = d; bc = code; }
            }
            atomicMin(&best[lrow], pack_key(bd, bc));
        }
    __syncthreads();
    if (t < 64) atomicMin(&gbest[m0 + t], best[t]);
}

__global__ void init_gbest(unsigned long long* __restrict__ g)
{
    g[blockIdx.x * 256 + threadIdx.x] = ~0ull;
}

// Gather z_q = codebook[idx] (fp32) and accumulate sum((z_q - z32)^2) in fp64.
__global__ void gather_zq_loss(const float* __restrict__ z, const float* __restrict__ cb,
                               const unsigned long long* __restrict__ gbest,
                               float* __restrict__ zq, double* __restrict__ acc)
{
    int r = blockIdx.x * 4 + (threadIdx.x >> 6);
    int lane = threadIdx.x & 63;
    int k = (int)(gbest[r] & 0xffffffffull);
    float2 zv = *(const float2*)(z  + (size_t)r * DDIM + lane * 2);
    float2 cv = *(const float2*)(cb + (size_t)k * DDIM + lane * 2);
    *(float2*)(zq + (size_t)r * DDIM + lane * 2) = cv;
    double dx = (double)cv.x - (double)zv.x, dy = (double)cv.y - (double)zv.y;
    double s = dx * dx + dy * dy;
#pragma unroll
    for (int off = 32; off > 0; off >>= 1) s += __shfl_down(s, off);
    if (lane == 0) atomicAdd(acc, s);
}

__global__ void zero_acc_kernel(double* acc)
{
    if (threadIdx.x == 0 && blockIdx.x == 0) *acc = 0.0;
}

__global__ void finalize_kernel(const unsigned long long* __restrict__ gbest,
                                const double* __restrict__ acc, float* __restrict__ out)
{
    int tid = blockIdx.x * 256 + threadIdx.x;
    if (tid < B_) out[16777217 + tid] = (float)(int)(gbest[tid] & 0xffffffffull);
    if (tid == 0) out[16777216] = (float)((*acc) * 1.25 / (double)(B_ * DDIM));
}

// ---------------------------------------------------------------------------
// One-time weight transpose+cvt: in fp32 [K][N] -> out bf16 [N][K].
// ---------------------------------------------------------------------------
__global__ void transpose_to_bf16(const float* __restrict__ in, __bf16* __restrict__ outT,
                                  int K, int N)
{
    __shared__ float tile[32][33];
    int k0 = blockIdx.x * 32, n0 = blockIdx.y * 32;
    int tr = threadIdx.x >> 5, tc = threadIdx.x & 31;
#pragma unroll
    for (int s = 0; s < 4; ++s)
        tile[tr + 8 * s][tc] = in[(size_t)(k0 + tr + 8 * s) * N + n0 + tc];
    __syncthreads();
#pragma unroll
    for (int s = 0; s < 4; ++s)
        outT[(size_t)(n0 + tr + 8 * s) * K + k0 + tc] = (__bf16)tile[tc][tr + 8 * s];
}

// ---------------------------------------------------------------------------
// bf16 MFMA GEMM (decoder, layout HW-validated R4): C = act(A@B + bias).
// ---------------------------------------------------------------------------
template <bool A_F32, int ACT>
__launch_bounds__(256)
__global__ void gemm_mfma(const void* __restrict__ Ap, const __bf16* __restrict__ BT,
                          const float* __restrict__ bias, void* __restrict__ Cp,
                          int M, int N, int K)
{
    __shared__ __bf16 Asm[128 * 32];
    __shared__ __bf16 Bsm[128 * 32];

    const int t    = threadIdx.x;
    const int m0   = blockIdx.y * 128, n0 = blockIdx.x * 128;
    const int wave = t >> 6, lane = t & 63;
    const int wr   = (wave >> 1) * 64, wc = (wave & 1) * 64;
    const int quad = lane >> 4, l16 = lane & 15;
    const int sr   = t >> 1, sh = t & 1;

    floatx4 acc[4][4];
#pragma unroll
    for (int i = 0; i < 4; ++i)
#pragma unroll
        for (int j = 0; j < 4; ++j) acc[i][j] = (floatx4){0.f, 0.f, 0.f, 0.f};

    for (int k0 = 0; k0 < K; k0 += 32) {
        if (A_F32) {
            const float* src = (const float*)Ap + (size_t)(m0 + sr) * K + k0 + sh * 16;
            __bf16 tmp[16];
#pragma unroll
            for (int q = 0; q < 4; ++q) {
                float4 v = *(const float4*)(src + q * 4);
                tmp[q * 4 + 0] = (__bf16)v.x; tmp[q * 4 + 1] = (__bf16)v.y;
                tmp[q * 4 + 2] = (__bf16)v.z; tmp[q * 4 + 3] = (__bf16)v.w;
            }
            *(bf16x8*)&Asm[sr * 32 + sh * 16 + 0] = *(bf16x8*)&tmp[0];
            *(bf16x8*)&Asm[sr * 32 + sh * 16 + 8] = *(bf16x8*)&tmp[8];
        } else {
            const __bf16* src = (const __bf16*)Ap + (size_t)(m0 + sr) * K + k0 + sh * 16;
            *(uint4*)&Asm[sr * 32 + sh * 16] = *(const uint4*)src;
            *(uint4*)&Asm[sr * 32 + sh * 16 + 8] = *(const uint4*)(src + 8);
        }
        {
            const __bf16* src = BT + (size_t)(n0 + sr) * K + k0 + sh * 16;
            *(uint4*)&Bsm[sr * 32 + sh * 16] = *(const uint4*)src;
            *(uint4*)&Bsm[sr * 32 + sh * 16 + 8] = *(const uint4*)(src + 8);
        }
        __syncthreads();
        bf16x8 af[4], bfr[4];
#pragma unroll
        for (int i = 0; i < 4; ++i)
            af[i] = *(const bf16x8*)&Asm[(wr + i * 16 + l16) * 32 + quad * 8];
#pragma unroll
        for (int j = 0; j < 4; ++j)
            bfr[j] = *(const bf16x8*)&Bsm[(wc + j * 16 + l16) * 32 + quad * 8];
#pragma unroll
        for (int i = 0; i < 4; ++i)
#pragma unroll
            for (int j = 0; j < 4; ++j)
                acc[i][j] = __builtin_amdgcn_mfma_f32_16x16x32_bf16(af[i], bfr[j], acc[i][j], 0, 0, 0);
        __syncthreads();
    }

#pragma unroll
    for (int i = 0; i < 4; ++i)
#pragma unroll
        for (int j = 0; j < 4; ++j) {
            int col = n0 + wc + j * 16 + l16;
            float b = bias[col];
#pragma unroll
            for (int r = 0; r < 4; ++r) {
                int row = m0 + wr + i * 16 + quad * 4 + r;
                float v = acc[i][j][r] + b;
                if (ACT == 1) {
                    v = fmaxf(v, 0.f);
                    ((__bf16*)Cp)[(size_t)row * N + col] = (__bf16)v;
                } else {
                    v = 1.f / (1.f + __expf(-v));
                    ((float*)Cp)[(size_t)row * N + col] = v;
                }
            }
        }
}

// ---------------------------------------------------------------------------
extern "C" void kernel_launch(void* const* d_in, const int* in_sizes, int n_in,
                              void* d_out, int out_size, void* d_ws, size_t ws_size,
                              hipStream_t stream)
{
    const float* x  = (const float*)d_in[0];
    const float* W1 = (const float*)d_in[1];
    const float* b1 = (const float*)d_in[2];
    const float* W2 = (const float*)d_in[3];
    const float* b2 = (const float*)d_in[4];
    const float* cb = (const float*)d_in[5];
    const float* W3 = (const float*)d_in[6];
    const float* b3 = (const float*)d_in[7];
    const float* W4 = (const float*)d_in[8];
    const float* b4 = (const float*)d_in[9];
    float* out = (float*)d_out;

    char* ws = (char*)d_ws;
    // h fp32 (128MB) live G1->G2 only; h2b bf16 (G3->G4) aliases at +16MB.
    float*  h    = (float*)(ws);
    __bf16* h2b  = (__bf16*)(ws + 16777216ull);       // 64 MB
    float*  z32  = (float*)(ws + 134217728ull);       //  8 MB
    float*  zq   = (float*)(ws + 142606336ull);       //  8 MB
    float*  nz32 = (float*)(ws + 150994944ull);       // 64 KB
    float*  cn32 = (float*)(ws + 151060480ull);       // 32 KB
    unsigned long long* gbest = (unsigned long long*)(ws + 151093248ull); // 128 KB
    double* acc  = (double*)(ws + 151224320ull);      // 8 B (4KB pad)
    __bf16* W3t  = (__bf16*)(ws + 151228416ull);      // 512 KB [2048][128]
    __bf16* W4t  = (__bf16*)(ws + 151752704ull);      //   4 MB [1024][2048]

    zero_acc_kernel<<<1, 64, 0, stream>>>(acc);
    init_gbest<<<B_ / 256, 256, 0, stream>>>(gbest);
    rownorm_kernel<<<KCB / 4, 256, 0, stream>>>(cb, cn32);
    transpose_to_bf16<<<dim3(DDIM / 32, HID / 32), 256, 0, stream>>>(W3, W3t, DDIM, HID);
    transpose_to_bf16<<<dim3(HID / 32, INDIM / 32), 256, 0, stream>>>(W4, W4t, HID, INDIM);

    // h = relu(fl32(x@W1 + b1)), f64 MFMA      [16384,1024]x[1024,2048]
    gemm_f64_mfma<1><<<dim3(HID / 64, B_ / 128), 256, 0, stream>>>(
        x, W1, b1, h, B_, HID, INDIM);
    // z32 = fl32(h@W2 + b2), f64 MFMA          [16384,2048]x[2048,128]
    gemm_f64_mfma<0><<<dim3(DDIM / 64, B_ / 128), 256, 0, stream>>>(
        h, W2, b2, z32, B_, DDIM, HID);
    // nz32 = fl32(sum fl32(z^2))
    rownorm_kernel<<<B_ / 4, 256, 0, stream>>>(z32, nz32);
    // f64-MFMA score + race-free fused argmin
    score_argmin_mfma<<<dim3(KCB / 128, B_ / 64), 256, 0, stream>>>(
        z32, cb, nz32, cn32, gbest);
    // z_q gather + commitment loss
    gather_zq_loss<<<B_ / 4, 256, 0, stream>>>(z32, cb, gbest, zq, acc);
    // h2 = relu(zq@W3 + b3) -> bf16            [16384,128]x[128,2048]
    gemm_mfma<true, 1><<<dim3(HID / 128, B_ / 128), 256, 0, stream>>>(
        (const void*)zq, W3t, b3, (void*)h2b, B_, HID, DDIM);
    // recon = sigmoid(h2@W4 + b4) -> fp32 out  [16384,2048]x[2048,1024]
    gemm_mfma<false, 2><<<dim3(INDIM / 128, B_ / 128), 256, 0, stream>>>(
        (const void*)h2b, W4t, b4, (void*)out, B_, INDIM, HID);

    finalize_kernel<<<B_ / 256, 256, 0, stream>>>(gbest, acc, out);
}

// Round 8
// 2516.393 us; speedup vs baseline: 1.2848x; 1.2848x over previous
//
#include <hip/hip_runtime.h>
#include <hip/hip_bf16.h>

// VQ-VAE forward. Index path: fp32-per-op semantics w/ fp64 internal accumulation
// via f64 MFMA. Staging via async global_load_lds (16B) into XOR-swizzled fp32 LDS
// (cvt-to-f64 at fragment read) -- no VGPR round trip, no spill risk (R7 lesson).
// Argmin via packed-key atomicMin. Decoder: bf16 MFMA.
// Outputs (flat fp32): recon[16384*1024], loss[1], indices-as-float[16384].

#define B_    16384
#define INDIM 1024
#define HID   2048
#define KCB   8192
#define DDIM  128

typedef __bf16  bf16x8   __attribute__((ext_vector_type(8)));
typedef float   floatx4  __attribute__((ext_vector_type(4)));
typedef double  doublex4 __attribute__((ext_vector_type(4)));

__device__ __forceinline__ unsigned long long pack_key(float d, int code)
{
    unsigned int u = __float_as_uint(d);
    u = (u & 0x80000000u) ? ~u : (u | 0x80000000u);   // total order matching float <
    return ((unsigned long long)u << 32) | (unsigned int)code;
}

// Async global->LDS, 16 B per lane. LDS dest: wave-uniform base + lane*16.
__device__ __forceinline__ void gll16(const float* g, float* l)
{
    __builtin_amdgcn_global_load_lds(
        (const __attribute__((address_space(1))) void*)g,
        (__attribute__((address_space(3))) void*)l, 16, 0, 0);
}

// ---------------------------------------------------------------------------
// fp32-in GEMM, f64 MFMA accumulate, single fp32 rounding (+opt relu).
// A [M][K] row-major, BT [N][K] row-major (pre-transposed). BM=128 BN=64 BK=32.
// 4 waves 2x2, wave tile 64x32 via 4x2 mfma_f64_16x16x4. m97-style 2-barrier
// K-loop with global_load_lds; LDS fp32 packed rows of 32 floats, chunk c of
// row r stored at position c ^ (r&7)  -> all reads <=2-way bank aliasing.
// ---------------------------------------------------------------------------
template <int ACT>
__launch_bounds__(256)
__global__ void gemm_f64_gll(const float* __restrict__ A, const float* __restrict__ BT,
                             const float* __restrict__ bias, float* __restrict__ Cout,
                             int M, int N, int K)
{
    __shared__ float As[128 * 32];
    __shared__ float Bs[64 * 32];

    const int t    = threadIdx.x;
    const int m0   = blockIdx.y * 128, n0 = blockIdx.x * 64;
    const int wave = t >> 6, lane = t & 63;
    const int wr   = (wave >> 1) * 64, wc = (wave & 1) * 32;
    const int quad = lane >> 4, l16 = lane & 15;
    const int lr   = lane >> 3;                 // row within 8-row staging group
    const int lc   = ((lane & 7) ^ lr) * 4;     // swizzled global col (floats)

    // Layout probe: self-correcting for any bijective C/D lane mapping.
    doublex4 p0 = {0.0, 0.0, 0.0, 0.0};
    doublex4 prow = __builtin_amdgcn_mfma_f64_16x16x4f64((double)l16, 1.0, p0, 0, 0, 0);
    doublex4 pcol = __builtin_amdgcn_mfma_f64_16x16x4f64(1.0, (double)l16, p0, 0, 0, 0);
    int rowmap[4], colmap[4];
#pragma unroll
    for (int r = 0; r < 4; ++r) {
        rowmap[r] = (int)(prow[r] * 0.25);
        colmap[r] = (int)(pcol[r] * 0.25);
    }

    doublex4 acc[4][2];
#pragma unroll
    for (int i = 0; i < 4; ++i)
#pragma unroll
        for (int j = 0; j < 2; ++j) acc[i][j] = (doublex4){0.0, 0.0, 0.0, 0.0};

    for (int k0 = 0; k0 < K; k0 += 32) {
        __syncthreads();   // previous compute done -> LDS reusable
#pragma unroll
        for (int s = 0; s < 4; ++s) {          // A: wave covers 32 rows
            int r = wave * 32 + s * 8;
            gll16(A + (size_t)(m0 + r + lr) * K + k0 + lc, &As[r * 32]);
        }
#pragma unroll
        for (int s = 0; s < 2; ++s) {          // B: wave covers 16 rows
            int r = wave * 16 + s * 8;
            gll16(BT + (size_t)(n0 + r + lr) * K + k0 + lc, &Bs[r * 32]);
        }
        __syncthreads();   // deposits visible (compiler drains vmcnt)
#pragma unroll
        for (int ks = 0; ks < 32; ks += 4) {
            const int cbase = (ks >> 2) ^ (l16 & 7);   // swizzled chunk
            double a[4], b[2];
#pragma unroll
            for (int i = 0; i < 4; ++i)
                a[i] = (double)As[(wr + i * 16 + l16) * 32 + cbase * 4 + quad];
#pragma unroll
            for (int j = 0; j < 2; ++j)
                b[j] = (double)Bs[(wc + j * 16 + l16) * 32 + cbase * 4 + quad];
#pragma unroll
            for (int i = 0; i < 4; ++i)
#pragma unroll
                for (int j = 0; j < 2; ++j)
                    acc[i][j] = __builtin_amdgcn_mfma_f64_16x16x4f64(a[i], b[j], acc[i][j], 0, 0, 0);
        }
    }

#pragma unroll
    for (int i = 0; i < 4; ++i)
#pragma unroll
        for (int j = 0; j < 2; ++j)
#pragma unroll
            for (int r = 0; r < 4; ++r) {
                int row = m0 + wr + i * 16 + rowmap[r];
                int col = n0 + wc + j * 16 + colmap[r];
                float f = (float)(acc[i][j][r] + (double)bias[col]);  // single fp32 round
                if (ACT == 1) f = fmaxf(f, 0.f);
                Cout[(size_t)row * N + col] = f;
            }
}

// ---------------------------------------------------------------------------
// rownorm32[k] = fl32( sum_fp64( fl32(row[k][d]^2) ) ). One wave per row.
// ---------------------------------------------------------------------------
__global__ void rownorm_kernel(const float* __restrict__ M, float* __restrict__ nrm)
{
    int k = blockIdx.x * 4 + (threadIdx.x >> 6);
    int lane = threadIdx.x & 63;
    float2 c = *(const float2*)(M + (size_t)k * DDIM + lane * 2);
    float q0 = c.x * c.x;
    float q1 = c.y * c.y;
    double s = (double)q0 + (double)q1;
#pragma unroll
    for (int off = 32; off > 0; off >>= 1) s += __shfl_down(s, off);
    if (lane == 0) nrm[k] = (float)s;
}

// ---------------------------------------------------------------------------
// Score: f64 MFMA z.c per (64-row,128-code) tile; gll staging as above.
// fp32 dist chain d = fl32(fl32(nz - 2*s32) + cn); packed-key LDS atomicMin
// -> global atomicMin. z [m][k] and cb [n][k] are naturally row-major-over-k.
// ---------------------------------------------------------------------------
__launch_bounds__(256)
__global__ void score_argmin_gll(const float* __restrict__ z, const float* __restrict__ cb,
                                 const float* __restrict__ nz32, const float* __restrict__ cn32,
                                 unsigned long long* __restrict__ gbest)
{
    __shared__ float zs[64 * 32];
    __shared__ float cs[128 * 32];
    __shared__ unsigned long long best[64];

    const int t    = threadIdx.x;
    const int m0   = blockIdx.y * 64;    // rows
    const int n0   = blockIdx.x * 128;   // codes
    const int wave = t >> 6, lane = t & 63;
    const int wr   = (wave >> 1) * 32, wc = (wave & 1) * 64;
    const int quad = lane >> 4, l16 = lane & 15;
    const int lr   = lane >> 3;
    const int lc   = ((lane & 7) ^ lr) * 4;

    if (t < 64) best[t] = ~0ull;

    doublex4 p0 = {0.0, 0.0, 0.0, 0.0};
    doublex4 prow = __builtin_amdgcn_mfma_f64_16x16x4f64((double)l16, 1.0, p0, 0, 0, 0);
    doublex4 pcol = __builtin_amdgcn_mfma_f64_16x16x4f64(1.0, (double)l16, p0, 0, 0, 0);
    int rowmap[4], colmap[4];
#pragma unroll
    for (int r = 0; r < 4; ++r) {
        rowmap[r] = (int)(prow[r] * 0.25);
        colmap[r] = (int)(pcol[r] * 0.25);
    }

    doublex4 acc[2][4];
#pragma unroll
    for (int i = 0; i < 2; ++i)
#pragma unroll
        for (int j = 0; j < 4; ++j) acc[i][j] = (doublex4){0.0, 0.0, 0.0, 0.0};

    for (int k0 = 0; k0 < DDIM; k0 += 32) {
        __syncthreads();
#pragma unroll
        for (int s = 0; s < 2; ++s) {          // z: wave covers 16 rows
            int r = wave * 16 + s * 8;
            gll16(z + (size_t)(m0 + r + lr) * DDIM + k0 + lc, &zs[r * 32]);
        }
#pragma unroll
        for (int s = 0; s < 4; ++s) {          // cb: wave covers 32 rows
            int r = wave * 32 + s * 8;
            gll16(cb + (size_t)(n0 + r + lr) * DDIM + k0 + lc, &cs[r * 32]);
        }
        __syncthreads();
#pragma unroll
        for (int ks = 0; ks < 32; ks += 4) {
            const int cbase = (ks >> 2) ^ (l16 & 7);
            double a[2], b[4];
#pragma unroll
            for (int i = 0; i < 2; ++i)
                a[i] = (double)zs[(wr + i * 16 + l16) * 32 + cbase * 4 + quad];
#pragma unroll
            for (int j = 0; j < 4; ++j)
                b[j] = (double)cs[(wc + j * 16 + l16) * 32 + cbase * 4 + quad];
#pragma unroll
            for (int i = 0; i < 2; ++i)
#pragma unroll
                for (int j = 0; j < 4; ++j)
                    acc[i][j] = __builtin_amdgcn_mfma_f64_16x16x4f64(a[i], b[j], acc[i][j], 0, 0, 0);
        }
    }

#pragma unroll
    for (int i = 0; i < 2; ++i)
#pragma unroll
        for (int r = 0; r < 4; ++r) {
            int   lrow = wr + i * 16 + rowmap[r];
            float nz   = nz32[m0 + lrow];
            float bd   = 3.4e38f; int bc = 0x7fffffff;
#pragma unroll
            for (int j = 0; j < 4; ++j) {
                int   code = n0 + wc + j * 16 + colmap[r];
                float s32  = (float)acc[i][j][r];
                float d    = (nz - 2.0f * s32) + cn32[code];
                if (d < bd || (d == bd && code < bc)) { bd = d; bc = code; }
            }
            atomicMin(&best[lrow], pack_key(bd, bc));
        }
    __syncthreads();
    if (t < 64) atomicMin(&gbest[m0 + t], best[t]);
}

__global__ void init_gbest(unsigned long long* __restrict__ g)
{
    g[blockIdx.x * 256 + threadIdx.x] = ~0ull;
}

// Gather z_q = codebook[idx] (fp32) and accumulate sum((z_q - z32)^2) in fp64.
__global__ void gather_zq_loss(const float* __restrict__ z, const float* __restrict__ cb,
                               const unsigned long long* __restrict__ gbest,
                               float* __restrict__ zq, double* __restrict__ acc)
{
    int r = blockIdx.x * 4 + (threadIdx.x >> 6);
    int lane = threadIdx.x & 63;
    int k = (int)(gbest[r] & 0xffffffffull);
    float2 zv = *(const float2*)(z  + (size_t)r * DDIM + lane * 2);
    float2 cv = *(const float2*)(cb + (size_t)k * DDIM + lane * 2);
    *(float2*)(zq + (size_t)r * DDIM + lane * 2) = cv;
    double dx = (double)cv.x - (double)zv.x, dy = (double)cv.y - (double)zv.y;
    double s = dx * dx + dy * dy;
#pragma unroll
    for (int off = 32; off > 0; off >>= 1) s += __shfl_down(s, off);
    if (lane == 0) atomicAdd(acc, s);
}

__global__ void zero_acc_kernel(double* acc)
{
    if (threadIdx.x == 0 && blockIdx.x == 0) *acc = 0.0;
}

__global__ void finalize_kernel(const unsigned long long* __restrict__ gbest,
                                const double* __restrict__ acc, float* __restrict__ out)
{
    int tid = blockIdx.x * 256 + threadIdx.x;
    if (tid < B_) out[16777217 + tid] = (float)(int)(gbest[tid] & 0xffffffffull);
    if (tid == 0) out[16777216] = (float)((*acc) * 1.25 / (double)(B_ * DDIM));
}

// ---------------------------------------------------------------------------
// One-time weight transposes: fp32 [K][N] -> bf16/fp32 [N][K].
// ---------------------------------------------------------------------------
__global__ void transpose_to_bf16(const float* __restrict__ in, __bf16* __restrict__ outT,
                                  int K, int N)
{
    __shared__ float tile[32][33];
    int k0 = blockIdx.x * 32, n0 = blockIdx.y * 32;
    int tr = threadIdx.x >> 5, tc = threadIdx.x & 31;
#pragma unroll
    for (int s = 0; s < 4; ++s)
        tile[tr + 8 * s][tc] = in[(size_t)(k0 + tr + 8 * s) * N + n0 + tc];
    __syncthreads();
#pragma unroll
    for (int s = 0; s < 4; ++s)
        outT[(size_t)(n0 + tr + 8 * s) * K + k0 + tc] = (__bf16)tile[tc][tr + 8 * s];
}

__global__ void transpose_f32(const float* __restrict__ in, float* __restrict__ outT,
                              int K, int N)
{
    __shared__ float tile[32][33];
    int k0 = blockIdx.x * 32, n0 = blockIdx.y * 32;
    int tr = threadIdx.x >> 5, tc = threadIdx.x & 31;
#pragma unroll
    for (int s = 0; s < 4; ++s)
        tile[tr + 8 * s][tc] = in[(size_t)(k0 + tr + 8 * s) * N + n0 + tc];
    __syncthreads();
#pragma unroll
    for (int s = 0; s < 4; ++s)
        outT[(size_t)(n0 + tr + 8 * s) * K + k0 + tc] = tile[tc][tr + 8 * s];
}

// ---------------------------------------------------------------------------
// bf16 MFMA GEMM (decoder, layout HW-validated R4): C = act(A@B + bias).
// ---------------------------------------------------------------------------
template <bool A_F32, int ACT>
__launch_bounds__(256)
__global__ void gemm_mfma(const void* __restrict__ Ap, const __bf16* __restrict__ BT,
                          const float* __restrict__ bias, void* __restrict__ Cp,
                          int M, int N, int K)
{
    __shared__ __bf16 Asm[128 * 32];
    __shared__ __bf16 Bsm[128 * 32];

    const int t    = threadIdx.x;
    const int m0   = blockIdx.y * 128, n0 = blockIdx.x * 128;
    const int wave = t >> 6, lane = t & 63;
    const int wr   = (wave >> 1) * 64, wc = (wave & 1) * 64;
    const int quad = lane >> 4, l16 = lane & 15;
    const int sr   = t >> 1, sh = t & 1;

    floatx4 acc[4][4];
#pragma unroll
    for (int i = 0; i < 4; ++i)
#pragma unroll
        for (int j = 0; j < 4; ++j) acc[i][j] = (floatx4){0.f, 0.f, 0.f, 0.f};

    for (int k0 = 0; k0 < K; k0 += 32) {
        if (A_F32) {
            const float* src = (const float*)Ap + (size_t)(m0 + sr) * K + k0 + sh * 16;
            __bf16 tmp[16];
#pragma unroll
            for (int q = 0; q < 4; ++q) {
                float4 v = *(const float4*)(src + q * 4);
                tmp[q * 4 + 0] = (__bf16)v.x; tmp[q * 4 + 1] = (__bf16)v.y;
                tmp[q * 4 + 2] = (__bf16)v.z; tmp[q * 4 + 3] = (__bf16)v.w;
            }
            *(bf16x8*)&Asm[sr * 32 + sh * 16 + 0] = *(bf16x8*)&tmp[0];
            *(bf16x8*)&Asm[sr * 32 + sh * 16 + 8] = *(bf16x8*)&tmp[8];
        } else {
            const __bf16* src = (const __bf16*)Ap + (size_t)(m0 + sr) * K + k0 + sh * 16;
            *(uint4*)&Asm[sr * 32 + sh * 16] = *(const uint4*)src;
            *(uint4*)&Asm[sr * 32 + sh * 16 + 8] = *(const uint4*)(src + 8);
        }
        {
            const __bf16* src = BT + (size_t)(n0 + sr) * K + k0 + sh * 16;
            *(uint4*)&Bsm[sr * 32 + sh * 16] = *(const uint4*)src;
            *(uint4*)&Bsm[sr * 32 + sh * 16 + 8] = *(const uint4*)(src + 8);
        }
        __syncthreads();
        bf16x8 af[4], bfr[4];
#pragma unroll
        for (int i = 0; i < 4; ++i)
            af[i] = *(const bf16x8*)&Asm[(wr + i * 16 + l16) * 32 + quad * 8];
#pragma unroll
        for (int j = 0; j < 4; ++j)
            bfr[j] = *(const bf16x8*)&Bsm[(wc + j * 16 + l16) * 32 + quad * 8];
#pragma unroll
        for (int i = 0; i < 4; ++i)
#pragma unroll
            for (int j = 0; j < 4; ++j)
                acc[i][j] = __builtin_amdgcn_mfma_f32_16x16x32_bf16(af[i], bfr[j], acc[i][j], 0, 0, 0);
        __syncthreads();
    }

#pragma unroll
    for (int i = 0; i < 4; ++i)
#pragma unroll
        for (int j = 0; j < 4; ++j) {
            int col = n0 + wc + j * 16 + l16;
            float b = bias[col];
#pragma unroll
            for (int r = 0; r < 4; ++r) {
                int row = m0 + wr + i * 16 + quad * 4 + r;
                float v = acc[i][j][r] + b;
                if (ACT == 1) {
                    v = fmaxf(v, 0.f);
                    ((__bf16*)Cp)[(size_t)row * N + col] = (__bf16)v;
                } else {
                    v = 1.f / (1.f + __expf(-v));
                    ((float*)Cp)[(size_t)row * N + col] = v;
                }
            }
        }
}

// ---------------------------------------------------------------------------
extern "C" void kernel_launch(void* const* d_in, const int* in_sizes, int n_in,
                              void* d_out, int out_size, void* d_ws, size_t ws_size,
                              hipStream_t stream)
{
    const float* x  = (const float*)d_in[0];
    const float* W1 = (const float*)d_in[1];
    const float* b1 = (const float*)d_in[2];
    const float* W2 = (const float*)d_in[3];
    const float* b2 = (const float*)d_in[4];
    const float* cb = (const float*)d_in[5];
    const float* W3 = (const float*)d_in[6];
    const float* b3 = (const float*)d_in[7];
    const float* W4 = (const float*)d_in[8];
    const float* b4 = (const float*)d_in[9];
    float* out = (float*)d_out;

    char* ws = (char*)d_ws;
    // h fp32 (128MB) live G1->G2 only; h2b bf16 (decoder) aliases at +16MB.
    // W1t (8MB, live only during G1) aliases zq (written later by gather).
    float*  h    = (float*)(ws);
    __bf16* h2b  = (__bf16*)(ws + 16777216ull);       // 64 MB
    float*  z32  = (float*)(ws + 134217728ull);       //  8 MB
    float*  zq   = (float*)(ws + 142606336ull);       //  8 MB
    float*  W1t  = (float*)(ws + 142606336ull);       //  8 MB (alias of zq)
    float*  nz32 = (float*)(ws + 150994944ull);       // 64 KB
    float*  cn32 = (float*)(ws + 151060480ull);       // 32 KB
    unsigned long long* gbest = (unsigned long long*)(ws + 151093248ull); // 128 KB
    double* acc  = (double*)(ws + 151224320ull);      // 8 B (4KB pad)
    __bf16* W3t  = (__bf16*)(ws + 151228416ull);      // 512 KB [2048][128]
    __bf16* W4t  = (__bf16*)(ws + 151752704ull);      //   4 MB [1024][2048]
    float*  W2t  = (float*)(ws + 155947008ull);       //   1 MB [128][2048]

    zero_acc_kernel<<<1, 64, 0, stream>>>(acc);
    init_gbest<<<B_ / 256, 256, 0, stream>>>(gbest);
    rownorm_kernel<<<KCB / 4, 256, 0, stream>>>(cb, cn32);
    transpose_to_bf16<<<dim3(DDIM / 32, HID / 32), 256, 0, stream>>>(W3, W3t, DDIM, HID);
    transpose_to_bf16<<<dim3(HID / 32, INDIM / 32), 256, 0, stream>>>(W4, W4t, HID, INDIM);
    transpose_f32<<<dim3(INDIM / 32, HID / 32), 256, 0, stream>>>(W1, W1t, INDIM, HID);
    transpose_f32<<<dim3(HID / 32, DDIM / 32), 256, 0, stream>>>(W2, W2t, HID, DDIM);

    // h = relu(fl32(x@W1 + b1)), f64 MFMA + gll   [16384,1024]x[1024,2048]
    gemm_f64_gll<1><<<dim3(HID / 64, B_ / 128), 256, 0, stream>>>(
        x, W1t, b1, h, B_, HID, INDIM);
    // z32 = fl32(h@W2 + b2), f64 MFMA + gll       [16384,2048]x[2048,128]
    gemm_f64_gll<0><<<dim3(DDIM / 64, B_ / 128), 256, 0, stream>>>(
        h, W2t, b2, z32, B_, DDIM, HID);
    // nz32 = fl32(sum fl32(z^2))
    rownorm_kernel<<<B_ / 4, 256, 0, stream>>>(z32, nz32);
    // f64-MFMA score + race-free fused argmin
    score_argmin_gll<<<dim3(KCB / 128, B_ / 64), 256, 0, stream>>>(
        z32, cb, nz32, cn32, gbest);
    // z_q gather + commitment loss
    gather_zq_loss<<<B_ / 4, 256, 0, stream>>>(z32, cb, gbest, zq, acc);
    // h2 = relu(zq@W3 + b3) -> bf16               [16384,128]x[128,2048]
    gemm_mfma<true, 1><<<dim3(HID / 128, B_ / 128), 256, 0, stream>>>(
        (const void*)zq, W3t, b3, (void*)h2b, B_, HID, DDIM);
    // recon = sigmoid(h2@W4 + b4) -> fp32 out     [16384,2048]x[2048,1024]
    gemm_mfma<false, 2><<<dim3(INDIM / 128, B_ / 128), 256, 0, stream>>>(
        (const void*)h2b, W4t, b4, (void*)out, B_, INDIM, HID);

    finalize_kernel<<<B_ / 256, 256, 0, stream>>>(gbest, acc, out);
}